// Round 9
// baseline (25610.037 us; speedup 1.0000x reference)
//
#include <hip/hip_runtime.h>

#define B_    256
#define L_    128
#define D_    6
#define F_    200
#define FA_   39
#define FB_   10
#define FAB_  49         // FA + FB
#define PAD_  127        // L-1 padding atom index
#define LMASK 127        // L-1, pow2 mask == exact clamp for idx in [0,L)
#define NT    256

__device__ __forceinline__ float lrelu(float x) { return x >= 0.0f ? x : 0.01f * x; }
__device__ __forceinline__ float sigm(float x)  { return 1.0f / (1.0f + __expf(-x)); }

// One block per node (b,l). Fully fused round: cur & nbr features, attention
// (masked softmax over D), context (attend matvec + elu), GRU cell.
// round 0 writes fp32 cur to d_ws; round 1 reads it and writes fp32 d_out.
__global__ __launch_bounds__(NT)
void fp_round_kernel(
    const float* __restrict__ atom_list,   // [B,L,FA] fp32
    const float* __restrict__ bond_list,   // [B,L,FB]
    const int*   __restrict__ atom_degree, // [B,L,D]
    const int*   __restrict__ bond_degree, // [B,L,D]
    const float* __restrict__ atom_W,      // [F,FA]
    const float* __restrict__ atom_b,      // [F]
    const float* __restrict__ nbr_W,       // [F,FAB]
    const float* __restrict__ nbr_b,       // [F]
    const float* __restrict__ align_W,     // [2F]  (this round)
    const float* __restrict__ align_b,     // [1]
    const float* __restrict__ attend_W,    // [F,F]
    const float* __restrict__ attend_b,    // [F]
    const float* __restrict__ gru_Wih,     // [3F,F]
    const float* __restrict__ gru_Whh,     // [3F,F]
    const float* __restrict__ gru_bih,     // [3F]
    const float* __restrict__ gru_bhh,     // [3F]
    const float* __restrict__ cur_in,      // [B,L,F] fp32 (round 1)
    float*       __restrict__ cur_out,     // [B,L,F] fp32 (ws or d_out)
    int round)
{
    const int node = blockIdx.x;          // b*L + l
    const int b    = node >> 7;
    const int tid  = threadIdx.x;

    __shared__ float cur_s[F_];
    __shared__ float nbr_s[D_][F_];
    __shared__ float ctx_s[F_];
    __shared__ float attn_s[D_];
    __shared__ int   nidx_s[D_];
    __shared__ int   bidx_s[D_];

    if (tid < D_) {
        nidx_s[tid] = atom_degree[node * D_ + tid] & LMASK;
        bidx_s[tid] = bond_degree[node * D_ + tid] & LMASK;
    }

    // ---- cur features for this node ----
    if (round == 0) {
        if (tid < F_) {
            const float* arow = atom_list + (size_t)node * FA_;
            const float* wrow = atom_W + (size_t)tid * FA_;
            float acc = atom_b[tid];
            #pragma unroll
            for (int k = 0; k < FA_; ++k) acc += arow[k] * wrow[k];
            cur_s[tid] = lrelu(acc);
        }
    } else {
        if (tid < F_) cur_s[tid] = cur_in[(size_t)node * F_ + tid];
    }
    __syncthreads();   // nidx/bidx + cur_s ready

    // ---- neighbor features ----
    if (round == 0) {
        for (int idx = tid; idx < D_ * F_; idx += NT) {
            const int j = idx / F_;
            const int f = idx - j * F_;
            const float* arow = atom_list + ((size_t)b * L_ + nidx_s[j]) * FA_;
            const float* brow = bond_list + ((size_t)b * L_ + bidx_s[j]) * FB_;
            const float* wrow = nbr_W + (size_t)f * FAB_;
            float acc = nbr_b[f];
            #pragma unroll
            for (int k = 0; k < FA_; ++k) acc += arow[k] * wrow[k];
            #pragma unroll
            for (int k = 0; k < FB_; ++k) acc += brow[k] * wrow[FA_ + k];
            nbr_s[j][f] = lrelu(acc);
        }
    } else {
        for (int idx = tid; idx < D_ * F_; idx += NT) {
            const int j = idx / F_;
            const int f = idx - j * F_;
            nbr_s[j][f] = cur_in[((size_t)b * L_ + nidx_s[j]) * F_ + f];
        }
    }
    __syncthreads();

    // ---- attention scores (threads 0..5) ----
    if (tid < D_) {
        float acc = align_b[0];
        for (int f = 0; f < F_; ++f)
            acc += cur_s[f] * align_W[f] + nbr_s[tid][f] * align_W[F_ + f];
        float sc = lrelu(acc);
        if (nidx_s[tid] == PAD_) sc += -9.0e8f;
        attn_s[tid] = sc;
    }
    __syncthreads();

    // ---- masked softmax over D (thread 0) ----
    if (tid == 0) {
        float m = attn_s[0];
        #pragma unroll
        for (int j = 1; j < D_; ++j) m = fmaxf(m, attn_s[j]);
        float ex[D_]; float s = 0.0f;
        #pragma unroll
        for (int j = 0; j < D_; ++j) { ex[j] = __expf(attn_s[j] - m); s += ex[j]; }
        const float inv = 1.0f / s;
        #pragma unroll
        for (int j = 0; j < D_; ++j)
            attn_s[j] = (nidx_s[j] == PAD_) ? 0.0f : ex[j] * inv;
    }
    __syncthreads();

    // ---- context = elu( sum_j attn[j] * (attend_W @ nbr[j] + attend_b) ) ----
    if (tid < F_) {
        const float* wrow = attend_W + (size_t)tid * F_;
        float s0=0.f,s1=0.f,s2=0.f,s3=0.f,s4=0.f,s5=0.f;
        for (int k = 0; k < F_; ++k) {
            const float w = wrow[k];     // per-lane row (L2-resident)
            s0 += w * nbr_s[0][k];       // LDS broadcast across lanes
            s1 += w * nbr_s[1][k];
            s2 += w * nbr_s[2][k];
            s3 += w * nbr_s[3][k];
            s4 += w * nbr_s[4][k];
            s5 += w * nbr_s[5][k];
        }
        const float bb = attend_b[tid];
        float c = attn_s[0]*(s0+bb) + attn_s[1]*(s1+bb) + attn_s[2]*(s2+bb)
                + attn_s[3]*(s3+bb) + attn_s[4]*(s4+bb) + attn_s[5]*(s5+bb);
        ctx_s[tid] = (c > 0.0f) ? c : (__expf(c) - 1.0f);   // elu
    }
    __syncthreads();

    // ---- GRU cell: input=ctx, hidden=cur ----
    if (tid < F_) {
        const float* wir = gru_Wih + (size_t)tid * F_;
        const float* wiz = gru_Wih + (size_t)(F_ + tid) * F_;
        const float* win = gru_Wih + (size_t)(2*F_ + tid) * F_;
        const float* whr = gru_Whh + (size_t)tid * F_;
        const float* whz = gru_Whh + (size_t)(F_ + tid) * F_;
        const float* whn = gru_Whh + (size_t)(2*F_ + tid) * F_;
        float ir = gru_bih[tid], iz = gru_bih[F_ + tid], inn = gru_bih[2*F_ + tid];
        float hr = gru_bhh[tid], hz = gru_bhh[F_ + tid], hn  = gru_bhh[2*F_ + tid];
        for (int k = 0; k < F_; ++k) {
            const float c = ctx_s[k];    // broadcast
            const float h = cur_s[k];    // broadcast
            ir += wir[k] * c; iz += wiz[k] * c; inn += win[k] * c;
            hr += whr[k] * h; hz += whz[k] * h; hn  += whn[k] * h;
        }
        const float r = sigm(ir + hr);
        const float z = sigm(iz + hz);
        const float n = tanhf(inn + r * hn);
        const float h = (1.0f - z) * n + z * cur_s[tid];
        cur_out[(size_t)node * F_ + tid] = fmaxf(h, 0.0f);
    }
}

extern "C" __attribute__((visibility("default")))
void kernel_launch(void* const* d_in, const int* in_sizes, int n_in,
                   void* d_out, int out_size, void* d_ws, size_t ws_size,
                   hipStream_t stream) {
    const float* atom_list = (const float*)d_in[0];
    const float* bond_list = (const float*)d_in[1];
    const int*   atom_deg  = (const int*)d_in[2];
    const int*   bond_deg  = (const int*)d_in[3];
    const float* atom_W    = (const float*)d_in[4];
    const float* atom_b    = (const float*)d_in[5];
    const float* nbr_W     = (const float*)d_in[6];
    const float* nbr_b     = (const float*)d_in[7];
    const float* align_W   = (const float*)d_in[8];   // [R,1,2F]
    const float* align_b   = (const float*)d_in[9];   // [R,1]
    const float* attend_W  = (const float*)d_in[10];  // [R,F,F]
    const float* attend_b  = (const float*)d_in[11];  // [R,F]
    const float* gru_Wih   = (const float*)d_in[12];  // [R,3F,F]
    const float* gru_Whh   = (const float*)d_in[13];  // [R,3F,F]
    const float* gru_bih   = (const float*)d_in[14];  // [R,3F]
    const float* gru_bhh   = (const float*)d_in[15];  // [R,3F]

    float* cur_ws = (float*)d_ws;      // [B,L,F] fp32, 26.2 MB (ws = 256 MB)
    float* out    = (float*)d_out;     // [B,L,F] fp32

    for (int d = 0; d < 2; ++d) {
        fp_round_kernel<<<dim3(B_ * L_), dim3(NT), 0, stream>>>(
            atom_list, bond_list, atom_deg, bond_deg,
            atom_W, atom_b, nbr_W, nbr_b,
            align_W + (size_t)d * 2 * F_,
            align_b + d,
            attend_W + (size_t)d * F_ * F_,
            attend_b + (size_t)d * F_,
            gru_Wih + (size_t)d * 3 * F_ * F_,
            gru_Whh + (size_t)d * 3 * F_ * F_,
            gru_bih + (size_t)d * 3 * F_,
            gru_bhh + (size_t)d * 3 * F_,
            cur_ws,
            (d == 1) ? out : cur_ws,
            d);
    }
}

// Round 10
// 2837.733 us; speedup vs baseline: 9.0248x; 9.0248x over previous
//
#include <hip/hip_runtime.h>

#define B_     256
#define L_     128
#define D_     6
#define F_     200
#define FA_    39
#define FB_    10
#define FAB_   49        // FA + FB
#define PAD_   127       // L-1 padding atom index
#define LMASK  127       // L-1 (pow2): exact clamp for idx in [0,L)
#define NT     256
#define NTILE  8         // nodes per block (divides L)
#define KC     (F_/4)    // 50 float4 chunks per row

__device__ __forceinline__ float lrelu(float x) { return x >= 0.0f ? x : 0.01f * x; }
__device__ __forceinline__ float sigm(float x)  { return 1.0f / (1.0f + __expf(-x)); }
__device__ __forceinline__ float dot4(float4 a, float4 b) {
    return a.x*b.x + a.y*b.y + a.z*b.z + a.w*b.w;
}

// One block = 8 nodes of one molecule. Per round:
//   A: cur features   B: neighbor features   C: align scores (quad-reduce)
//   softmax           D: mixed = sum_j attn_j*nbr_j   (algebraic collapse)
//   E: ctx = elu(attend_W @ mixed + asum*b)           F: GRU cell
__global__ __launch_bounds__(NT)
void fp_round_kernel(
    const float* __restrict__ atom_list,   // [B,L,FA]
    const float* __restrict__ bond_list,   // [B,L,FB]
    const int*   __restrict__ atom_degree, // [B,L,D]
    const int*   __restrict__ bond_degree, // [B,L,D]
    const float* __restrict__ atom_W,      // [F,FA]
    const float* __restrict__ atom_b,      // [F]
    const float* __restrict__ nbr_W,       // [F,FAB]
    const float* __restrict__ nbr_b,       // [F]
    const float* __restrict__ align_W,     // [2F]   (this round)
    const float* __restrict__ align_b,     // [1]
    const float* __restrict__ attend_W,    // [F,F]
    const float* __restrict__ attend_b,    // [F]
    const float* __restrict__ gru_Wih,     // [3F,F]
    const float* __restrict__ gru_Whh,     // [3F,F]
    const float* __restrict__ gru_bih,     // [3F]
    const float* __restrict__ gru_bhh,     // [3F]
    const float* __restrict__ cur_in,      // [B,L,F] (round 1)
    float*       __restrict__ cur_out,     // [B,L,F] (ws or d_out)
    int round)
{
    const int node0 = blockIdx.x * NTILE;       // first node of tile
    const int b     = node0 >> 7;               // molecule (NTILE | L)
    const int tid   = threadIdx.x;

    __shared__ __align__(16) float cur_s  [NTILE][F_];
    __shared__ __align__(16) float nbr_s  [NTILE * D_][F_];
    __shared__ __align__(16) float mixed_s[NTILE][F_];
    __shared__ __align__(16) float ctx_s  [NTILE][F_];
    __shared__ float alW_s[2 * F_];
    __shared__ float sc_s [NTILE * D_];        // scores -> attn
    __shared__ float asum_s[NTILE];
    __shared__ int   nidx_s[NTILE * D_];
    __shared__ int   bidx_s[NTILE * D_];
    __shared__ __align__(16) float ga_s[NTILE * D_][FAB_ + 1]; // r0 gathered rows (+1 pad)

    // ---- neighbor indices + align weights ----
    if (tid < NTILE * D_) {
        const int n = tid / D_, j = tid - n * D_;
        nidx_s[tid] = atom_degree[(node0 + n) * D_ + j] & LMASK;
        bidx_s[tid] = bond_degree[(node0 + n) * D_ + j] & LMASK;
    }
    for (int i = tid; i < 2 * F_; i += NT) alW_s[i] = align_W[i];

    // ---- Phase A: cur features ----
    if (round == 0) {
        for (int idx = tid; idx < NTILE * F_; idx += NT) {
            const int n = idx / F_, f = idx - n * F_;
            const float* arow = atom_list + (size_t)(node0 + n) * FA_;
            const float* wrow = atom_W + (size_t)f * FA_;
            float acc = atom_b[f];
            #pragma unroll
            for (int k = 0; k < FA_; ++k) acc += arow[k] * wrow[k];
            cur_s[n][f] = lrelu(acc);
        }
    } else {
        for (int idx = tid; idx < NTILE * F_; idx += NT) {
            const int n = idx / F_, f = idx - n * F_;
            cur_s[n][f] = cur_in[(size_t)(node0 + n) * F_ + f];
        }
    }
    __syncthreads();   // nidx/bidx, alW, cur_s ready

    // ---- Phase B: neighbor features ----
    if (round == 0) {
        // stage gathered atom+bond rows
        for (int idx = tid; idx < NTILE * D_ * FAB_; idx += NT) {
            const int q = idx / FAB_, k = idx - q * FAB_;
            ga_s[q][k] = (k < FA_)
                ? atom_list[(size_t)(b * L_ + nidx_s[q]) * FA_ + k]
                : bond_list[(size_t)(b * L_ + bidx_s[q]) * FB_ + (k - FA_)];
        }
        __syncthreads();
        for (int idx = tid; idx < NTILE * D_ * F_; idx += NT) {
            const int q = idx / F_, f = idx - q * F_;
            const float* g    = ga_s[q];
            const float* wrow = nbr_W + (size_t)f * FAB_;
            float acc = nbr_b[f];
            #pragma unroll
            for (int k = 0; k < FAB_; ++k) acc += g[k] * wrow[k];
            nbr_s[q][f] = lrelu(acc);
        }
    } else {
        for (int idx = tid; idx < NTILE * D_ * F_; idx += NT) {
            const int q = idx / F_, f = idx - q * F_;
            nbr_s[q][f] = cur_in[(size_t)(b * L_ + nidx_s[q]) * F_ + f];
        }
    }
    __syncthreads();

    // ---- Phase C: align scores (one quad of lanes per (n,j)) ----
    if (tid < NTILE * D_ * 4) {
        const int quad = tid >> 2, sub = tid & 3;   // quad 0..47
        const int n = quad / D_;
        const int k0 = sub * 100;
        float s = 0.0f;
        for (int i = 0; i < 100; ++i) {
            const int k = k0 + i;                  // 0..399
            const float v = (k < F_) ? cur_s[n][k] : nbr_s[quad][k - F_];
            s += v * alW_s[k];
        }
        s += __shfl_xor(s, 1, 4);
        s += __shfl_xor(s, 2, 4);
        if (sub == 0) {
            float sc = lrelu(s + align_b[0]);
            if (nidx_s[quad] == PAD_) sc += -9.0e8f;
            sc_s[quad] = sc;
        }
    }
    __syncthreads();

    // ---- masked softmax over D per node ----
    if (tid < NTILE) {
        float m = sc_s[tid * D_];
        #pragma unroll
        for (int j = 1; j < D_; ++j) m = fmaxf(m, sc_s[tid * D_ + j]);
        float ex[D_]; float ssum = 0.0f;
        #pragma unroll
        for (int j = 0; j < D_; ++j) { ex[j] = __expf(sc_s[tid * D_ + j] - m); ssum += ex[j]; }
        const float inv = 1.0f / ssum;
        float as = 0.0f;
        #pragma unroll
        for (int j = 0; j < D_; ++j) {
            const float a = (nidx_s[tid * D_ + j] == PAD_) ? 0.0f : ex[j] * inv;
            sc_s[tid * D_ + j] = a;   // now attn
            as += a;
        }
        asum_s[tid] = as;
    }
    __syncthreads();

    // ---- Phase D: mixed[n][k] = sum_j attn[n][j] * nbr[n][j][k] ----
    for (int idx = tid; idx < NTILE * F_; idx += NT) {
        const int n = idx / F_, k = idx - n * F_;
        float m = 0.0f;
        #pragma unroll
        for (int j = 0; j < D_; ++j) m += sc_s[n * D_ + j] * nbr_s[n * D_ + j][k];
        mixed_s[n][k] = m;
    }
    __syncthreads();

    // ---- Phase E: ctx[n][f] = elu( attend_W[f]·mixed[n] + asum[n]*attend_b[f] ) ----
    if (tid < F_) {
        float acc[NTILE];
        #pragma unroll
        for (int n = 0; n < NTILE; ++n) acc[n] = 0.0f;
        const float4* w4 = (const float4*)(attend_W + (size_t)tid * F_);
        for (int kk = 0; kk < KC; ++kk) {
            const float4 w = w4[kk];
            #pragma unroll
            for (int n = 0; n < NTILE; ++n)
                acc[n] += dot4(w, ((const float4*)mixed_s[n])[kk]);
        }
        const float bb = attend_b[tid];
        #pragma unroll
        for (int n = 0; n < NTILE; ++n) {
            const float c = acc[n] + asum_s[n] * bb;
            ctx_s[n][tid] = (c > 0.0f) ? c : (__expf(c) - 1.0f);
        }
    }
    __syncthreads();

    // ---- Phase F: GRU cell for 8 nodes ----
    if (tid < F_) {
        float air[NTILE], aiz[NTILE], ain[NTILE], ahr[NTILE], ahz[NTILE], ahn[NTILE];
        #pragma unroll
        for (int n = 0; n < NTILE; ++n)
            air[n] = aiz[n] = ain[n] = ahr[n] = ahz[n] = ahn[n] = 0.0f;

        const float4* wir4 = (const float4*)(gru_Wih + (size_t)tid * F_);
        const float4* wiz4 = (const float4*)(gru_Wih + (size_t)(F_   + tid) * F_);
        const float4* win4 = (const float4*)(gru_Wih + (size_t)(2*F_ + tid) * F_);
        const float4* whr4 = (const float4*)(gru_Whh + (size_t)tid * F_);
        const float4* whz4 = (const float4*)(gru_Whh + (size_t)(F_   + tid) * F_);
        const float4* whn4 = (const float4*)(gru_Whh + (size_t)(2*F_ + tid) * F_);

        for (int kk = 0; kk < KC; ++kk) {
            const float4 wr = wir4[kk], wz = wiz4[kk], wn = win4[kk];
            const float4 vr = whr4[kk], vz = whz4[kk], vn = whn4[kk];
            #pragma unroll
            for (int n = 0; n < NTILE; ++n) {
                const float4 c = ((const float4*)ctx_s[n])[kk];
                const float4 h = ((const float4*)cur_s[n])[kk];
                air[n] += dot4(wr, c); aiz[n] += dot4(wz, c); ain[n] += dot4(wn, c);
                ahr[n] += dot4(vr, h); ahz[n] += dot4(vz, h); ahn[n] += dot4(vn, h);
            }
        }
        const float bir = gru_bih[tid], biz = gru_bih[F_ + tid], bin = gru_bih[2*F_ + tid];
        const float bhr = gru_bhh[tid], bhz = gru_bhh[F_ + tid], bhn = gru_bhh[2*F_ + tid];
        #pragma unroll
        for (int n = 0; n < NTILE; ++n) {
            const float r  = sigm(air[n] + bir + ahr[n] + bhr);
            const float z  = sigm(aiz[n] + biz + ahz[n] + bhz);
            const float nn = tanhf(ain[n] + bin + r * (ahn[n] + bhn));
            const float h  = (1.0f - z) * nn + z * cur_s[n][tid];
            cur_out[(size_t)(node0 + n) * F_ + tid] = fmaxf(h, 0.0f);
        }
    }
}

extern "C" __attribute__((visibility("default")))
void kernel_launch(void* const* d_in, const int* in_sizes, int n_in,
                   void* d_out, int out_size, void* d_ws, size_t ws_size,
                   hipStream_t stream) {
    const float* atom_list = (const float*)d_in[0];
    const float* bond_list = (const float*)d_in[1];
    const int*   atom_deg  = (const int*)d_in[2];
    const int*   bond_deg  = (const int*)d_in[3];
    const float* atom_W    = (const float*)d_in[4];
    const float* atom_b    = (const float*)d_in[5];
    const float* nbr_W     = (const float*)d_in[6];
    const float* nbr_b     = (const float*)d_in[7];
    const float* align_W   = (const float*)d_in[8];   // [R,1,2F]
    const float* align_b   = (const float*)d_in[9];   // [R,1]
    const float* attend_W  = (const float*)d_in[10];  // [R,F,F]
    const float* attend_b  = (const float*)d_in[11];  // [R,F]
    const float* gru_Wih   = (const float*)d_in[12];  // [R,3F,F]
    const float* gru_Whh   = (const float*)d_in[13];  // [R,3F,F]
    const float* gru_bih   = (const float*)d_in[14];  // [R,3F]
    const float* gru_bhh   = (const float*)d_in[15];  // [R,3F]

    float* cur_ws = (float*)d_ws;      // [B,L,F] fp32, 26.2 MB (ws = 256 MB)
    float* out    = (float*)d_out;     // [B,L,F] fp32

    const dim3 grid(B_ * L_ / NTILE);  // 4096
    const dim3 block(NT);

    for (int d = 0; d < 2; ++d) {
        fp_round_kernel<<<grid, block, 0, stream>>>(
            atom_list, bond_list, atom_deg, bond_deg,
            atom_W, atom_b, nbr_W, nbr_b,
            align_W + (size_t)d * 2 * F_,
            align_b + d,
            attend_W + (size_t)d * F_ * F_,
            attend_b + (size_t)d * F_,
            gru_Wih + (size_t)d * 3 * F_ * F_,
            gru_Whh + (size_t)d * 3 * F_ * F_,
            gru_bih + (size_t)d * 3 * F_,
            gru_bhh + (size_t)d * 3 * F_,
            cur_ws,
            (d == 1) ? out : cur_ws,
            d);
    }
}